// Round 23
// baseline (338.794 us; speedup 1.0000x reference)
//
#include <hip/hip_runtime.h>

// TwoLayerSNN forward: B=256, T=1000, D=32, H=200, O=2
// Round 23: TRUE TLP via h-split + two kernels.
//  K1: grid 512 = 2 blocks/batch (h-half each), block 256 (4 waves):
//      w0-1 consumers (100 h: recurrence + s1/m1 stores + 4-level DPP),
//      w2-3 producers (r15's exact per-h dot chain, 50 h/wave; x staging),
//      w3 also merges per-t half-sums (lane-parallel 8tx8p 3-level DPP)
//      and writes float2 half-sums to d_ws (4 MB).
//  K2: grid 256, block 64: stages its batch's half-sums (16 KB) to LDS and
//      runs the validated r14 pk layer-2 chain; writes s2/m2/out.
// 2 independent 4-wave blocks/CU -> barrier bubbles of one filled by the
// other (r21-proven packing), with ZERO redundant compute.
// Dot + layer-1 recurrence bit-identical to r15. Layer-2 drive order:
// fadd(halfA, halfB) of exact-product sums (order change validated in r16).

constexpr int TB = 256;
constexpr int TT = 1000;
constexpr int DD = 32;
constexpr int HH = 200;
constexpr int OO = 2;
constexpr int CH = 40;                    // timesteps per x staging chunk
constexpr int NCH = TT / CH;              // 25
constexpr int SC = 8;                     // timesteps per barrier interval
constexpr int NSC = TT / SC;              // 125
constexpr int XF4 = CH * DD / 4;          // 320 float4 per chunk

typedef float v2f __attribute__((ext_vector_type(2)));

__device__ __forceinline__ v2f pk_fma(v2f a, v2f b, v2f c) {
#if __has_builtin(__builtin_elementwise_fma)
    return __builtin_elementwise_fma(a, b, c);
#else
    v2f r; r.x = fmaf(a.x, b.x, c.x); r.y = fmaf(a.y, b.y, c.y); return r;
#endif
}

template <int CTRL>
__device__ __forceinline__ float dpp_add(float v) {
    int t = __builtin_amdgcn_update_dpp(0, __float_as_int(v), CTRL, 0xf, 0xf, true);
    return v + __int_as_float(t);
}

__device__ __forceinline__ void block_sync_lds() {
    asm volatile("s_waitcnt lgkmcnt(0)" ::: "memory");
    __builtin_amdgcn_s_barrier();
    asm volatile("" ::: "memory");
}

// ---------------- Kernel 1: layer-1 (h-split) + half-sum export ----------------
__global__ __launch_bounds__(256)
void snn_l1(const float* __restrict__ x,
            const float* __restrict__ w1,
            const float* __restrict__ w2,
            float* __restrict__ out,
            float* __restrict__ ws)
{
    const int b    = blockIdx.x >> 1;
    const int half = blockIdx.x & 1;            // h in [half*100, half*100+100)
    const int tid  = threadIdx.x;
    const int lane = tid & 63;
    const int wid  = tid >> 6;
    const bool is_cons = (wid < 2);
    const bool is_prod = (wid >= 2);
    const bool is_mrg  = (wid == 3);
    const int ptid = tid - 128;                 // producer-local 0..127
    const bool act = is_cons && (tid < 100);    // consumer's local h = tid

    float* __restrict__ s1o = out + (size_t)TB * OO;
    float* __restrict__ m1o = s1o + (size_t)TB * TT * HH;

    const float A_SYN1 = (float)0.8187307530779818;
    const float IN_SC1 = (float)((1.0 - 0.8187307530779818) * 5.0);
    const float A_MEM1 = (float)0.9048374180359595;
    const float B_MEM1 = (float)(1.0 - 0.9048374180359595);
    const float TH1    = 0.5f;

    __shared__ float4 xls[2][XF4];                   // 2 x 5 KB
    __shared__ float  dotb[2][SC][128];              // 2 x 4 KB (padded OOB-safe)
    __shared__ __align__(16) float2 partv[2][SC][8]; // 1 KB

    const float* __restrict__ xb = x + (size_t)b * TT * DD;

    // producer weights: local h = (wid-2)*50 + lane, global col = half*100 + h
    const int phl  = (wid - 2) * 50 + lane;
    const bool pact = is_prod && (lane < 50);
    const int gcol = half * 100 + phl;
    v2f w1e[8], w1o[8];
#pragma unroll
    for (int i = 0; i < 8; ++i) {
        w1e[i] = pact ? v2f{w1[(4 * i) * HH + gcol],     w1[(4 * i + 1) * HH + gcol]} : v2f{0.f, 0.f};
        w1o[i] = pact ? v2f{w1[(4 * i + 2) * HH + gcol], w1[(4 * i + 3) * HH + gcol]} : v2f{0.f, 0.f};
    }
    // consumer w2 for global h = half*100 + tid
    const float w2x = act ? w2[(half * 100 + tid) * OO + 0] : 0.0f;
    const float w2y = act ? w2[(half * 100 + tid) * OO + 1] : 0.0f;

    // stage chunk 0 (producers, direct): 320 float4 over 128 threads
    if (is_prod) {
        const float4* g = (const float4*)xb;
        xls[0][ptid]       = g[ptid];
        xls[0][ptid + 128] = g[ptid + 128];
        if (ptid < 64) xls[0][ptid + 256] = g[ptid + 256];
    }
    block_sync_lds();

    // produce(j): dots for sub-chunk j into dotb[j&1][s][phl] — r15's exact
    // per-h chain (A01/A23 pk pairing, same merge order -> bit-identical).
    auto produce = [&](int j) {
        const int tj = j * SC;
        const float4* xq = &xls[(tj / CH) & 1][(tj % CH) * (DD / 4)];
#pragma unroll
        for (int s = 0; s < SC; ++s) {
            v2f A01 = {0.f, 0.f}, A23 = {0.f, 0.f};
            {
                const float4 X0 = xq[s * 8 + 0], X1 = xq[s * 8 + 1];
                const float4 X2 = xq[s * 8 + 2], X3 = xq[s * 8 + 3];
                A01 = pk_fma(v2f{X0.x, X0.y}, w1e[0], A01);
                A23 = pk_fma(v2f{X0.z, X0.w}, w1o[0], A23);
                A01 = pk_fma(v2f{X1.x, X1.y}, w1e[1], A01);
                A23 = pk_fma(v2f{X1.z, X1.w}, w1o[1], A23);
                A01 = pk_fma(v2f{X2.x, X2.y}, w1e[2], A01);
                A23 = pk_fma(v2f{X2.z, X2.w}, w1o[2], A23);
                A01 = pk_fma(v2f{X3.x, X3.y}, w1e[3], A01);
                A23 = pk_fma(v2f{X3.z, X3.w}, w1o[3], A23);
            }
            {
                const float4 X4 = xq[s * 8 + 4], X5 = xq[s * 8 + 5];
                const float4 X6 = xq[s * 8 + 6], X7 = xq[s * 8 + 7];
                A01 = pk_fma(v2f{X4.x, X4.y}, w1e[4], A01);
                A23 = pk_fma(v2f{X4.z, X4.w}, w1o[4], A23);
                A01 = pk_fma(v2f{X5.x, X5.y}, w1e[5], A01);
                A23 = pk_fma(v2f{X5.z, X5.w}, w1o[5], A23);
                A01 = pk_fma(v2f{X6.x, X6.y}, w1e[6], A01);
                A23 = pk_fma(v2f{X6.z, X6.w}, w1o[6], A23);
                A01 = pk_fma(v2f{X7.x, X7.y}, w1e[7], A01);
                A23 = pk_fma(v2f{X7.z, X7.w}, w1o[7], A23);
            }
            const float dotv = __fadd_rn(__fadd_rn(A01.x, A01.y),
                                         __fadd_rn(A23.x, A23.y));
            if (pact) dotb[j & 1][s][phl] = dotv;
        }
    };

    if (is_prod) produce(0);
    block_sync_lds();

    float syn1 = 0.0f, mem1 = 0.0f;
    float4 pr0, pr1, pr2;                 // persistent staging regs (r6 lesson)

    float* __restrict__ s1p = s1o + (size_t)b * TT * HH + half * 100 + tid;
    float* __restrict__ m1p = m1o + (size_t)b * TT * HH + half * 100 + tid;

    // wave 3: merge 8 partials/t for sub-chunk j, write half-sums to ws.
    // lane = s*8 + p ; 3-level DPP sums 8-lane groups; sums at (lane&7)==7.
    auto merge_ws = [&](int j) {
        const int s = lane >> 3, p = lane & 7;
        const float2 v = partv[j & 1][s][p];
        float cx = v.x, cy = v.y;
        cx = dpp_add<0x111>(cx); cy = dpp_add<0x111>(cy);
        cx = dpp_add<0x112>(cx); cy = dpp_add<0x112>(cy);
        cx = dpp_add<0x114>(cx); cy = dpp_add<0x114>(cy);
        if ((lane & 7) == 7) {
            const int t = j * SC + s;
            float2* wp = (float2*)&ws[((size_t)b * TT + t) * 4 + half * 2];
            *wp = make_float2(cx, cy);
        }
    };

    for (int sc = 0; sc < NSC; ++sc) {
        const int t0 = sc * SC;
        const int c  = sc / 5;            // 5 sub-chunks per chunk

        if (is_cons) {
            float D[SC];
#pragma unroll
            for (int s = 0; s < SC; ++s) D[s] = dotb[sc & 1][s][tid];

#pragma unroll
            for (int s = 0; s < SC; ++s) {
                const float dot = D[s];
                syn1 = __fadd_rn(__fmul_rn(A_SYN1, syn1), __fmul_rn(IN_SC1, dot));
                mem1 = __fadd_rn(__fmul_rn(A_MEM1, mem1), __fmul_rn(B_MEM1, syn1));
                const float s1v = (mem1 - TH1 > 0.0f) ? 1.0f : 0.0f;
                mem1 = __fsub_rn(mem1, __fmul_rn(s1v, TH1));

                if (act) {
                    s1p[(size_t)(t0 + s) * HH] = s1v;
                    m1p[(size_t)(t0 + s) * HH] = mem1;
                }

                float cx = s1v * w2x;     // exact products (s1v in {0,1})
                float cy = s1v * w2y;
                cx = dpp_add<0x111>(cx); cy = dpp_add<0x111>(cy);
                cx = dpp_add<0x112>(cx); cy = dpp_add<0x112>(cy);
                cx = dpp_add<0x114>(cx); cy = dpp_add<0x114>(cy);
                cx = dpp_add<0x118>(cx); cy = dpp_add<0x118>(cy);
                if ((lane & 15) == 15)
                    partv[sc & 1][s][wid * 4 + (lane >> 4)] = make_float2(cx, cy);
            }
        } else {
            // staging loads for chunk c+1
            if ((sc % 5) == 0 && c + 1 < NCH) {
                const float4* g = (const float4*)(xb + (size_t)(c + 1) * CH * DD);
                pr0 = g[ptid];
                pr1 = g[ptid + 128];
                if (ptid < 64) pr2 = g[ptid + 256];
            }

            if (sc + 1 < NSC) produce(sc + 1);

            if ((sc % 5) == 3 && c + 1 < NCH) {
                const int bn = (c + 1) & 1;
                xls[bn][ptid]       = pr0;
                xls[bn][ptid + 128] = pr1;
                if (ptid < 64) xls[bn][ptid + 256] = pr2;
            }

            if (is_mrg && sc > 0) merge_ws(sc - 1);
        }

        block_sync_lds();
    }

    if (is_mrg) merge_ws(NSC - 1);
}

// ---------------- Kernel 2: layer-2 serial chain from half-sums ----------------
__global__ __launch_bounds__(64)
void snn_l2(const float* __restrict__ ws,
            float* __restrict__ out)
{
#pragma clang fp contract(off)
    const int b    = blockIdx.x;
    const int lane = threadIdx.x;

    float* __restrict__ outp = out;
    float* __restrict__ s2o  = out + (size_t)TB * OO + 2 * (size_t)TB * TT * HH;
    float* __restrict__ m2o  = s2o + (size_t)TB * TT * OO;

    const float A_SYN2 = (float)0.9048374180359595;
    const float IN_SC2 = (float)((1.0 - 0.9048374180359595) * 10.0);
    const float A_MEM2 = (float)0.9512294245007140;
    const float B_MEM2 = (float)(1.0 - 0.9512294245007140);
    const float TH2    = 1.0f;

    __shared__ float4 wsl[TT];           // 16 KB: [cxA, cyA, cxB, cyB] per t

    const float4* wq = (const float4*)(ws + (size_t)b * TT * 4);
    for (int i = lane; i < TT; i += 64) wsl[i] = wq[i];
    block_sync_lds();

    v2f syn2 = {0.f, 0.f}, mem2 = {0.f, 0.f};
    const v2f A2v  = {A_SYN2, A_SYN2};
    const v2f SC2v = {IN_SC2, IN_SC2};
    const v2f AM2v = {A_MEM2, A_MEM2};
    const v2f BM2v = {B_MEM2, B_MEM2};
    const v2f TH2v = {TH2, TH2};
    double accx = 0.0, accy = 0.0;

    float2* __restrict__ s2p = (float2*)(s2o + (size_t)b * TT * OO);
    float2* __restrict__ m2p = (float2*)(m2o + (size_t)b * TT * OO);

    // all lanes run the chain redundantly (no divergence); lane 0 stores
    for (int t = 0; t < TT; ++t) {
        const float4 f = wsl[t];
        const v2f d = {__fadd_rn(f.x, f.z), __fadd_rn(f.y, f.w)};
        syn2 = (A2v * syn2) + (SC2v * d);
        mem2 = (AM2v * mem2) + (BM2v * syn2);
        const float s2x = (mem2.x - TH2 > 0.0f) ? 1.0f : 0.0f;
        const float s2y = (mem2.y - TH2 > 0.0f) ? 1.0f : 0.0f;
        const v2f s2v = {s2x, s2y};
        mem2 = mem2 - (s2v * TH2v);
        if (lane == 0) {
            s2p[t] = make_float2(s2x, s2y);
            m2p[t] = make_float2(mem2.x, mem2.y);
        }
        if (t > 0) { accx += (double)mem2.x; accy += (double)mem2.y; }
    }
    if (lane == 0) {
        outp[b * OO + 0] = (float)accx / 1000.0f;
        outp[b * OO + 1] = (float)accy / 1000.0f;
    }
}

extern "C" void kernel_launch(void* const* d_in, const int* in_sizes, int n_in,
                              void* d_out, int out_size, void* d_ws, size_t ws_size,
                              hipStream_t stream) {
    const float* x  = (const float*)d_in[0];   // [256,1000,32]
    const float* w1 = (const float*)d_in[1];   // [32,200]
    const float* w2 = (const float*)d_in[2];   // [200,2]
    float* out = (float*)d_out;
    float* ws  = (float*)d_ws;                 // 256*1000*4 floats = 4 MB

    hipLaunchKernelGGL(snn_l1, dim3(2 * TB), dim3(256), 0, stream, x, w1, w2, out, ws);
    hipLaunchKernelGGL(snn_l2, dim3(TB), dim3(64), 0, stream, ws, out);
}

// Round 24
// 182.274 us; speedup vs baseline: 1.8587x; 1.8587x over previous
//
#include <hip/hip_runtime.h>

// TwoLayerSNN forward: B=256, T=1000, D=32, H=200, O=2
// Round 24 = round 15 VERBATIM (best validated: 182us, absmax 0.015625).
// Rounds 16-23 exhausted the TLP program (reducer waves, 2x redundancy,
// VGPR bucketing, LDS pool, 8-wave blocks, h-split two-kernel): co-residency
// achieved (r21: 43%, r23: 21%) but never beat this single-block/CU form —
// the per-block produce->barrier->consume chain is the binding constraint
// and extra blocks only share issue slots. Op-count cuts (r10, r13) were
// the only consistent wins. This is the plateau kernel.

constexpr int TB = 256;
constexpr int TT = 1000;
constexpr int DD = 32;
constexpr int HH = 200;
constexpr int OO = 2;
constexpr int CH = 40;                    // timesteps per x staging chunk (5 KB)
constexpr int NCH = TT / CH;              // 25
constexpr int SC = 20;                    // timesteps per barrier interval
constexpr int NSC = TT / SC;              // 50
constexpr int XF4 = CH * DD / 4;          // 320 float4 per chunk

typedef float v2f __attribute__((ext_vector_type(2)));

__device__ __forceinline__ v2f pk_fma(v2f a, v2f b, v2f c) {
#if __has_builtin(__builtin_elementwise_fma)
    return __builtin_elementwise_fma(a, b, c);
#else
    v2f r; r.x = fmaf(a.x, b.x, c.x); r.y = fmaf(a.y, b.y, c.y); return r;
#endif
}

template <int CTRL>
__device__ __forceinline__ float dpp_add(float v) {
    int t = __builtin_amdgcn_update_dpp(0, __float_as_int(v), CTRL, 0xf, 0xf, true);
    return v + __int_as_float(t);
}

__device__ __forceinline__ float read_lane_f(float v, int l) {
    return __int_as_float(__builtin_amdgcn_readlane(__float_as_int(v), l));
}

__device__ __forceinline__ void block_sync_lds() {
    // Order LDS only (validated r8-r23): drain lgkm, raw barrier.
    asm volatile("s_waitcnt lgkmcnt(0)" ::: "memory");
    __builtin_amdgcn_s_barrier();
    asm volatile("" ::: "memory");
}

__global__ __launch_bounds__(576, 1)
void snn_fwd(const float* __restrict__ x,
             const float* __restrict__ w1,
             const float* __restrict__ w2,
             float* __restrict__ out)
{
    const int b    = blockIdx.x;
    const int tid  = threadIdx.x;
    const int lane = tid & 63;
    const int wid  = tid >> 6;
    const bool is_cons = (wid < 4);             // waves 0-3: consumers
    const bool is_prod = (wid >= 4 && wid < 8); // waves 4-7: producers
    const int ptid = tid - 256;                 // producer-local 0..255
    const bool act = is_cons && (tid < HH);

    float* __restrict__ outp = out;                        // [TB][OO]
    float* __restrict__ s1o  = out + (size_t)TB * OO;      // [TB][TT][HH]
    float* __restrict__ m1o  = s1o + (size_t)TB * TT * HH; // [TB][TT][HH]
    float* __restrict__ s2o  = m1o + (size_t)TB * TT * HH; // [TB][TT][OO]
    float* __restrict__ m2o  = s2o + (size_t)TB * TT * OO; // [TB][TT][OO]

    const float A_SYN1 = (float)0.8187307530779818;
    const float IN_SC1 = (float)((1.0 - 0.8187307530779818) * 5.0);
    const float A_MEM1 = (float)0.9048374180359595;
    const float B_MEM1 = (float)(1.0 - 0.9048374180359595);
    const float TH1    = 0.5f;
    const float A_SYN2 = (float)0.9048374180359595;
    const float IN_SC2 = (float)((1.0 - 0.9048374180359595) * 10.0);
    const float A_MEM2 = (float)0.9512294245007140;
    const float B_MEM2 = (float)(1.0 - 0.9512294245007140);
    const float TH2    = 1.0f;

    __shared__ float4 xls[2][XF4];                    // 2 x 5 KB
    __shared__ float  dotb[2][SC][HH];                // 2 x 16 KB
    __shared__ __align__(16) float2 partv[2][SC][16]; // 2 x 2.5 KB

    const float* __restrict__ xb = x + (size_t)b * TT * DD;

    // producer: 50 hidden units per wave; w1 column as 16 float2 pairs
    const int ph   = (wid - 4) * 50 + lane;          // producer h
    const bool pact = is_prod && (lane < 50);
    v2f w1e[DD / 4], w1o[DD / 4];
#pragma unroll
    for (int i = 0; i < DD / 4; ++i) {
        w1e[i] = pact ? v2f{w1[(4 * i) * HH + ph],     w1[(4 * i + 1) * HH + ph]} : v2f{0.f, 0.f};
        w1o[i] = pact ? v2f{w1[(4 * i + 2) * HH + ph], w1[(4 * i + 3) * HH + ph]} : v2f{0.f, 0.f};
    }
    // consumer: w2 row
    const float w2x = act ? w2[tid * OO + 0] : 0.0f;
    const float w2y = act ? w2[tid * OO + 1] : 0.0f;

    // stage chunk 0 (5 KB, 320 float4) using consumer threads (one-time)
    if (is_cons) {
        const float4* g = (const float4*)xb;
        if (2 * tid     < XF4) xls[0][2 * tid]     = g[2 * tid];
        if (2 * tid + 1 < XF4) xls[0][2 * tid + 1] = g[2 * tid + 1];
    }
    block_sync_lds();

    // produce(j): dots for sub-chunk j into dotb[j&1]. Same fma chain as
    // r10/r13/r14; 1-step-ahead register prefetch of the x block.
    auto produce = [&](int j) {
        const float4* xq = &xls[(j >> 1) & 1][(j & 1) * SC * (DD / 4)];
        float4 Xc0 = xq[0], Xc1 = xq[1], Xc2 = xq[2], Xc3 = xq[3];
        float4 Xc4 = xq[4], Xc5 = xq[5], Xc6 = xq[6], Xc7 = xq[7];
#pragma unroll
        for (int s = 0; s < SC; ++s) {
            float4 Xn0, Xn1, Xn2, Xn3, Xn4, Xn5, Xn6, Xn7;
            if (s < SC - 1) {
                const float4* nq = xq + (s + 1) * 8;
                Xn0 = nq[0]; Xn1 = nq[1]; Xn2 = nq[2]; Xn3 = nq[3];
                Xn4 = nq[4]; Xn5 = nq[5]; Xn6 = nq[6]; Xn7 = nq[7];
            }
            v2f A01 = {0.f, 0.f}, A23 = {0.f, 0.f};
            A01 = pk_fma(v2f{Xc0.x, Xc0.y}, w1e[0], A01);
            A23 = pk_fma(v2f{Xc0.z, Xc0.w}, w1o[0], A23);
            A01 = pk_fma(v2f{Xc1.x, Xc1.y}, w1e[1], A01);
            A23 = pk_fma(v2f{Xc1.z, Xc1.w}, w1o[1], A23);
            A01 = pk_fma(v2f{Xc2.x, Xc2.y}, w1e[2], A01);
            A23 = pk_fma(v2f{Xc2.z, Xc2.w}, w1o[2], A23);
            A01 = pk_fma(v2f{Xc3.x, Xc3.y}, w1e[3], A01);
            A23 = pk_fma(v2f{Xc3.z, Xc3.w}, w1o[3], A23);
            A01 = pk_fma(v2f{Xc4.x, Xc4.y}, w1e[4], A01);
            A23 = pk_fma(v2f{Xc4.z, Xc4.w}, w1o[4], A23);
            A01 = pk_fma(v2f{Xc5.x, Xc5.y}, w1e[5], A01);
            A23 = pk_fma(v2f{Xc5.z, Xc5.w}, w1o[5], A23);
            A01 = pk_fma(v2f{Xc6.x, Xc6.y}, w1e[6], A01);
            A23 = pk_fma(v2f{Xc6.z, Xc6.w}, w1o[6], A23);
            A01 = pk_fma(v2f{Xc7.x, Xc7.y}, w1e[7], A01);
            A23 = pk_fma(v2f{Xc7.z, Xc7.w}, w1o[7], A23);
            const float dotv = __fadd_rn(__fadd_rn(A01.x, A01.y),
                                         __fadd_rn(A23.x, A23.y));
            if (pact) dotb[j & 1][s][ph] = dotv;
            if (s < SC - 1) {
                Xc0 = Xn0; Xc1 = Xn1; Xc2 = Xn2; Xc3 = Xn3;
                Xc4 = Xn4; Xc5 = Xn5; Xc6 = Xn6; Xc7 = Xn7;
            }
        }
    };

    // prologue: fill dotb[0] for sub-chunk 0
    if (is_prod) produce(0);
    block_sync_lds();

    float syn1 = 0.0f, mem1 = 0.0f;
    double accx = 0.0, accy = 0.0;
    v2f syn2 = {0.f, 0.f}, mem2 = {0.f, 0.f};
    const v2f A2v  = {A_SYN2, A_SYN2};
    const v2f SC2v = {IN_SC2, IN_SC2};
    const v2f AM2v = {A_MEM2, A_MEM2};
    const v2f BM2v = {B_MEM2, B_MEM2};
    const v2f TH2v = {TH2, TH2};

    float* __restrict__ s1p = s1o + (size_t)b * TT * HH + tid;
    float* __restrict__ m1p = m1o + (size_t)b * TT * HH + tid;
    float2* __restrict__ s2p = (float2*)(s2o + (size_t)b * TT * OO);
    float2* __restrict__ m2p = (float2*)(m2o + (size_t)b * TT * OO);

    // layer-2 for sub-chunk j (wave 8 only): lane-parallel merge of the 16
    // row-partials (4 steps per pass, 5 passes), then the pk-packed serial
    // chain (per-component roundings identical to scalar __f*_rn; r14).
    auto l2_chunk = [&](int j) {
#pragma clang fp contract(off)
        const int g = lane >> 4;     // step within pass (0..3)
        const int p = lane & 15;     // partial index
#pragma unroll
        for (int half = 0; half < SC / 4; ++half) {
            const float2 v = partv[j & 1][4 * half + g][p];
            float cxv = v.x, cyv = v.y;
            cxv = dpp_add<0x111>(cxv); cyv = dpp_add<0x111>(cyv);
            cxv = dpp_add<0x112>(cxv); cyv = dpp_add<0x112>(cyv);
            cxv = dpp_add<0x114>(cxv); cyv = dpp_add<0x114>(cyv);
            cxv = dpp_add<0x118>(cxv); cyv = dpp_add<0x118>(cyv);
            // merged sums at lanes 15/31/47/63 for steps 4*half+0..3
#pragma unroll
            for (int gg = 0; gg < 4; ++gg) {
                const v2f d = {read_lane_f(cxv, 16 * gg + 15),
                               read_lane_f(cyv, 16 * gg + 15)};
                syn2 = (A2v * syn2) + (SC2v * d);
                mem2 = (AM2v * mem2) + (BM2v * syn2);
                const float s2x = (mem2.x - TH2 > 0.0f) ? 1.0f : 0.0f;
                const float s2y = (mem2.y - TH2 > 0.0f) ? 1.0f : 0.0f;
                const v2f s2v = {s2x, s2y};
                mem2 = mem2 - (s2v * TH2v);
                const int t = j * SC + 4 * half + gg;
                if (tid == 512) {
                    s2p[t] = make_float2(s2x, s2y);
                    m2p[t] = make_float2(mem2.x, mem2.y);
                }
                if (t > 0) { accx += (double)mem2.x; accy += (double)mem2.y; }
            }
        }
    };

    for (int sc = 0; sc < NSC; ++sc) {
        const int t0   = sc * SC;
        const int c    = t0 / CH;
        const int cpos = t0 % CH;

        if (is_cons) {
            // ---- consumer: this sub-chunk's dots from LDS ----
            float D[SC];
#pragma unroll
            for (int s = 0; s < SC; ++s) D[s] = dotb[sc & 1][s][tid];

            // ---- 20 steps: recurrence + stores + 4-level DPP (r13/r14) ----
#pragma unroll
            for (int s = 0; s < SC; ++s) {
                const float dot = D[s];
                syn1 = __fadd_rn(__fmul_rn(A_SYN1, syn1), __fmul_rn(IN_SC1, dot));
                mem1 = __fadd_rn(__fmul_rn(A_MEM1, mem1), __fmul_rn(B_MEM1, syn1));
                const float s1v = (mem1 - TH1 > 0.0f) ? 1.0f : 0.0f;
                mem1 = __fsub_rn(mem1, __fmul_rn(s1v, TH1));

                if (act) {
                    s1p[(size_t)(t0 + s) * HH] = s1v;
                    m1p[(size_t)(t0 + s) * HH] = mem1;
                }

                float cx = s1v * w2x;
                float cy = s1v * w2y;
                cx = dpp_add<0x111>(cx); cy = dpp_add<0x111>(cy);
                cx = dpp_add<0x112>(cx); cy = dpp_add<0x112>(cy);
                cx = dpp_add<0x114>(cx); cy = dpp_add<0x114>(cy);
                cx = dpp_add<0x118>(cx); cy = dpp_add<0x118>(cy);
                // row sums at lanes 15/31/47/63 -> 4 partials per wave
                if ((lane & 15) == 15)
                    partv[sc & 1][s][wid * 4 + (lane >> 4)] = make_float2(cx, cy);
            }
        } else if (is_prod) {
            // ---- producer: stage next chunk (same-iteration load/commit);
            //      compute next sub-chunk's dots ----
            float4 pr0, pr1;
            const bool stage = (cpos == 0 && c + 1 < NCH);
            if (stage) {
                const float4* g = (const float4*)(xb + (size_t)(c + 1) * CH * DD);
                if (2 * ptid     < XF4) pr0 = g[2 * ptid];
                if (2 * ptid + 1 < XF4) pr1 = g[2 * ptid + 1];
            }

            if (sc + 1 < NSC) produce(sc + 1);

            if (stage) {
                if (2 * ptid     < XF4) xls[(c + 1) & 1][2 * ptid]     = pr0;
                if (2 * ptid + 1 < XF4) xls[(c + 1) & 1][2 * ptid + 1] = pr1;
            }
        } else {
            // ---- wave 8: layer-2 for the previous sub-chunk ----
            if (sc > 0) l2_chunk(sc - 1);
        }

        block_sync_lds();
    }

    // epilogue: layer-2 for the final sub-chunk (wave 8)
    if (wid == 8) {
        l2_chunk(NSC - 1);
        if (tid == 512) {
            outp[b * OO + 0] = (float)accx / 1000.0f;
            outp[b * OO + 1] = (float)accy / 1000.0f;
        }
    }
}

extern "C" void kernel_launch(void* const* d_in, const int* in_sizes, int n_in,
                              void* d_out, int out_size, void* d_ws, size_t ws_size,
                              hipStream_t stream) {
    const float* x  = (const float*)d_in[0];   // [256,1000,32]
    const float* w1 = (const float*)d_in[1];   // [32,200]
    const float* w2 = (const float*)d_in[2];   // [200,2]
    float* out = (float*)d_out;

    dim3 grid(TB), block(576);
    hipLaunchKernelGGL(snn_fwd, grid, block, 0, stream, x, w1, w2, out);
}